// Round 11
// baseline (113.788 us; speedup 1.0000x reference)
//
#include <hip/hip_runtime.h>
#include <math.h>

#define NBINS   8192
#define L_AUDIO 16777216
#define T_FRAMES 2049
#define NQ      8400
#define MUNK    8188

__device__ __forceinline__ int refl_idx(int m) {
    if (m < 0) m = -m;
    if (m >= L_AUDIO) m = 2 * L_AUDIO - 2 - m;
    return m;
}
__device__ __forceinline__ float2 cmul(float2 a, float2 b) {
    return make_float2(fmaf(a.x, b.x, -a.y * b.y), fmaf(a.x, b.y, a.y * b.x));
}
__device__ __forceinline__ float2 csq(float2 a) {
    return make_float2(fmaf(a.x, a.x, -a.y * a.y), 2.0f * a.x * a.y);
}
// Gentleman-Sande radix-4: w_r = W_L^{r*q0}; output r stays at q0 + r*L/4.
// With unit twiddles (q0=0), slot r holds bin-residue r (identity map).
__device__ __forceinline__ void r4(float2& x0, float2& x1, float2& x2, float2& x3,
                                   float2 w1, float2 w2, float2 w3) {
    float2 t0 = make_float2(x0.x + x2.x, x0.y + x2.y);
    float2 t1 = make_float2(x1.x + x3.x, x1.y + x3.y);
    float2 t2 = make_float2(x0.x - x2.x, x0.y - x2.y);
    float2 t3 = make_float2(x1.x - x3.x, x1.y - x3.y);
    float2 b1 = make_float2(t2.x + t3.y, t2.y - t3.x);   // t2 - i*t3
    float2 b3 = make_float2(t2.x - t3.y, t2.y + t3.x);   // t2 + i*t3
    x0 = make_float2(t0.x + t1.x, t0.y + t1.y);
    x1 = cmul(w1, b1);
    x2 = cmul(w2, make_float2(t0.x - t1.x, t0.y - t1.y));
    x3 = cmul(w3, b3);
}
// radix-8 on 8 elems at q0 + j*L/8; all twiddles derived from w = W_L^{q0}.
// Output slot j holds bin-residue rho(j) = (j&1)*4 + (j>>1)  [derived r8 map].
__device__ __forceinline__ void r8(float2 x[8], float2 w) {
    const float c = 0.70710678118654752f;
    float2 w2 = csq(w), w3 = cmul(w, w2), w4 = csq(w2);
    r4(x[0], x[2], x[4], x[6], w, w2, w3);
    float2 wE   = make_float2(c * (w.x + w.y),  c * (w.y - w.x));     // w*e^{-i pi/4}
    float2 w2E2 = make_float2(w2.y, -w2.x);                           // w2*(-i)
    float2 w3E3 = make_float2(c * (w3.y - w3.x), -c * (w3.x + w3.y)); // w3*e^{-i3pi/4}
    r4(x[1], x[3], x[5], x[7], wE, w2E2, w3E3);
#pragma unroll
    for (int r = 0; r < 4; ++r) {
        float2 a = x[2 * r], b = x[2 * r + 1];
        x[2 * r]     = make_float2(a.x + b.x, a.y + b.y);
        float2 d     = make_float2(a.x - b.x, a.y - b.y);
        x[2 * r + 1] = cmul(w4, d);
    }
}
// inverse of rho: slot index holding residue r in an r8 output group
__device__ __forceinline__ int jof(int r) {
    return ((r >> 1) & 1) * 4 + (r & 1) * 2 + (r >> 2);
}
// position of logical bin m in the 2048-pt [8,8,8,4] GS chain output
// (final radix-4 has unit twiddles -> identity slot map for the top digit)
__device__ __forceinline__ int posOf2048(int m) {
    return 256 * jof(m & 7) + 32 * jof((m >> 3) & 7)
         + 4 * jof((m >> 6) & 7) + (m >> 9);
}

// ---------------- Kernel A: 512 threads, in-place 8192-pt complex FFT as
// 3x radix-8 + fused (radix-8 x2 + radix-2 in regs); window+pack fused into
// pass 1. Split mode (fmax==2048): every block does exactly 4 frames; frame
// 2048 is computed by blocks 4..7 as 4 decimated 2048-pt FFTs (r8-r10).
// Round-11: register-resident untangle. Thread t's pass-4+5 registers hold
// the final FFT values at positions [16t,16t+16); PB(s)/16 = g(s) is a bit
// permutation, so thread t now untangles bin-class s = g^{-1}(t) with its
// OWN registers as the A-side (was: 16 redundant LDS A-reads/frame) and
// reads only the partner class tb = g((512-s)&511) from LDS. Same values,
// same FP expressions, same order -> bit-exact; acc is re-coalesced through
// LDS once at the end. Saves 16/144 LDS ops/frame + the untangle A-stall.
__global__ __launch_bounds__(512, 2) void fft_pow_kernel(
        const float* __restrict__ audio, float* __restrict__ partial, int P,
        int fmax, float* __restrict__ Fout) {
    __shared__ float2 buf[8718];   // phi(p) = p + (p>>4) + (p>>9), max 8717
    const int t = threadIdx.x;

    if (blockIdx.x == 0 && t == 0) {   // counter lives at spec[8188]
        unsigned int* cz = (unsigned int*)(partial - 4);
        cz[0] = 0u;
    }

    const int phit  = t + (t >> 4);                         // phi(t), t < 512
    const int q2    = t & 127;
    const int base2 = 1090 * (t >> 7) + q2 + (q2 >> 4);     // pass2 base
    const int base3 = 136 * (t >> 4) + ((t >> 4) >> 2) + (t & 15);
    const int base4 = 17 * t + (t >> 5);
    // bin-class s with position-group g(s) == t (g = PB/16 bit-permutation):
    // s bits from t bits: s0=t7 s1=t8 s2=t6 s3=t4 s4=t5 s5=t3 s6=t1 s7=t2 s8=t0
    const int s  = ((t >> 7) & 1) | (((t >> 8) & 1) << 1) | (((t >> 6) & 1) << 2)
                 | (((t >> 4) & 1) << 3) | (((t >> 5) & 1) << 4)
                 | (((t >> 3) & 1) << 5) | (((t >> 1) & 1) << 6)
                 | (((t >> 2) & 1) << 7) | ((t & 1) << 8);
    const int sp = (512 - s) & 511;     // mirror class
    const int tb = (sp & 3) * 128 + ((sp >> 2) & 1) * 64 + ((sp >> 3) & 3) * 16
                 + ((sp >> 5) & 1) * 8 + ((sp >> 6) & 3) * 2 + ((sp >> 8) & 1);
    const int bB = 17 * tb + (tb >> 5); // phi(16*tb) = LDS base of mirror group

    const float2 ONE = make_float2(1.0f, 0.0f);
    const float2 K8  = make_float2(0.92387953251128674f, -0.38268343236508977f); // e^{-i pi/8}
    const float2 KD  = make_float2(0.99999992646574f, -0.00038349518757f);       // e^{-i pi/8192}
    float2 wU  = make_float2(cospif((float)t * (1.0f / 8192.0f)),
                             -sinpif((float)t * (1.0f / 8192.0f)));  // W_16384^t
    float2 w1  = csq(wU);                                            // W_8192^t
    float2 wodd = cmul(w1, KD);                                      // e^{-i pi(2t+1)/8192}
    float2 wUs = make_float2(cospif((float)s * (1.0f / 8192.0f)),
                             -sinpif((float)s * (1.0f / 8192.0f)));  // W_16384^s
    float2 w2t = make_float2(cospif((float)q2 * (1.0f / 512.0f)),
                             -sinpif((float)q2 * (1.0f / 512.0f)));  // W_1024^(t&127)
    float2 w3t = make_float2(cospif((float)(t & 15) * (1.0f / 64.0f)),
                             -sinpif((float)(t & 15) * (1.0f / 64.0f))); // W_128^(t&15)
    const float K16c[16] = {1.0f, 0.98078528040323044f, 0.92387953251128674f,
        0.83146961230254524f, 0.70710678118654752f, 0.55557023301960222f,
        0.38268343236508977f, 0.19509032201612825f, 0.0f, -0.19509032201612825f,
        -0.38268343236508977f, -0.55557023301960222f, -0.70710678118654752f,
        -0.83146961230254524f, -0.92387953251128674f, -0.98078528040323044f};
    const float K16s[16] = {0.0f, -0.19509032201612825f, -0.38268343236508977f,
        -0.55557023301960222f, -0.70710678118654752f, -0.83146961230254524f,
        -0.92387953251128674f, -0.98078528040323044f, -1.0f, -0.98078528040323044f,
        -0.92387953251128674f, -0.83146961230254524f, -0.70710678118654752f,
        -0.55557023301960222f, -0.38268343236508977f, -0.19509032201612825f};
    // window rotation: cos/sin(pi u/8), u in [0,16)
    const float W16C[16] = {1.0f, 0.92387953251128674f, 0.70710678118654752f,
        0.38268343236508977f, 0.0f, -0.38268343236508977f, -0.70710678118654752f,
        -0.92387953251128674f, -1.0f, -0.92387953251128674f, -0.70710678118654752f,
        -0.38268343236508977f, 0.0f, 0.38268343236508977f, 0.70710678118654752f,
        0.92387953251128674f};
    const float W16S[16] = {0.0f, 0.38268343236508977f, 0.70710678118654752f,
        0.92387953251128674f, 1.0f, 0.92387953251128674f, 0.70710678118654752f,
        0.38268343236508977f, 0.0f, -0.38268343236508977f, -0.70710678118654752f,
        -0.92387953251128674f, -1.0f, -0.92387953251128674f, -0.70710678118654752f,
        -0.38268343236508977f};

    float acc[16];
#pragma unroll
    for (int u = 0; u < 16; ++u) acc[u] = 0.0f;

    for (int f = blockIdx.x; f < fmax; f += P) {
        __syncthreads();   // previous frame's untangle B-reads vs pass-1 writes
        // ---- pass 1 (fused window+pack): L=8192, q0 = t + 512g ----
        const bool interior = (f != 0) && (f != T_FRAMES - 1);
        const float2* au2 = (const float2*)audio + 4096 * (f - 1);
        const int baseS = f * 8192 - 8192;
#pragma unroll 1
        for (int g = 0; g < 2; ++g) {
            float2 x[8];
            if (interior) {
#pragma unroll
                for (int j = 0; j < 8; ++j) {
                    int idx = t + 512 * g + 1024 * j;
                    float2 p = au2[idx];
                    const int uix = g + 2 * j;
                    float c0 = 0.5f - 0.5f * (w1.x * W16C[uix] + w1.y * W16S[uix]);
                    float c1 = 0.5f - 0.5f * (wodd.x * W16C[uix] + wodd.y * W16S[uix]);
                    x[j] = make_float2(p.x * c0, p.y * c1);
                }
            } else {
#pragma unroll
                for (int j = 0; j < 8; ++j) {
                    int idx = t + 512 * g + 1024 * j;
                    float a0 = audio[refl_idx(baseS + 2 * idx)];
                    float a1 = audio[refl_idx(baseS + 2 * idx + 1)];
                    const int uix = g + 2 * j;
                    float c0 = 0.5f - 0.5f * (w1.x * W16C[uix] + w1.y * W16S[uix]);
                    float c1 = 0.5f - 0.5f * (wodd.x * W16C[uix] + wodd.y * W16S[uix]);
                    x[j] = make_float2(a0 * c0, a1 * c1);
                }
            }
            float2 w = g ? cmul(w1, K8) : w1;
            r8(x, w);
#pragma unroll
            for (int j = 0; j < 8; ++j) buf[phit + 545 * g + 1090 * j] = x[j];
        }
        __syncthreads();
        // pass 2: L=1024, B = (t>>7)+4g, q0 = t&127, stride 128
#pragma unroll 1
        for (int g = 0; g < 2; ++g) {
            float2 x[8];
            const int bs = base2 + 4360 * g;
#pragma unroll
            for (int j = 0; j < 8; ++j) x[j] = buf[bs + 136 * j + (j >> 2)];
            r8(x, w2t);
#pragma unroll
            for (int j = 0; j < 8; ++j) buf[bs + 136 * j + (j >> 2)] = x[j];
        }
        __syncthreads();
        // pass 3: L=128, B = (t>>4)+32g, q0 = t&15, stride 16
#pragma unroll 1
        for (int g = 0; g < 2; ++g) {
            float2 x[8];
            const int bs = base3 + 4360 * g;
#pragma unroll
            for (int j = 0; j < 8; ++j) x[j] = buf[bs + 17 * j];
            r8(x, w3t);
#pragma unroll
            for (int j = 0; j < 8; ++j) buf[bs + 17 * j] = x[j];
        }
        __syncthreads();
        // pass 4+5 fused + register-resident untangle
        {
            float2 a[8], x[8];
#pragma unroll
            for (int j = 0; j < 8; ++j) a[j] = buf[base4 + 2 * j];
            r8(a, ONE);
#pragma unroll
            for (int j = 0; j < 8; ++j) x[j] = buf[base4 + 1 + 2 * j];
            r8(x, K8);
#pragma unroll
            for (int j = 0; j < 8; ++j) {
                float2 sj = make_float2(a[j].x + x[j].x, a[j].y + x[j].y);
                float2 dj = make_float2(a[j].x - x[j].x, a[j].y - x[j].y);
                buf[base4 + 2 * j]     = sj;
                buf[base4 + 2 * j + 1] = dj;
                a[j] = sj;               // keep: final values at even offsets
                x[j] = dj;               // keep: final values at odd offsets
            }
            __syncthreads();
            // untangle bins s+512u: A = own regs (slot off(u)), B = partner
            // group tb in LDS at off(u2). Same floats as the old LDS A-path.
#pragma unroll
            for (int u = 0; u < 16; ++u) {
                const int m = 2 * (u & 3) + ((u >> 2) & 1);
                float2 A = (u < 8) ? a[m] : x[m];
                int u2 = s ? (15 - u) : ((16 - u) & 15);
                int off2 = (u2 & 3) * 4 + ((u2 >> 2) & 1) * 2 + (u2 >> 3);
                float2 B = buf[bB + off2];
                float Xer = 0.5f * (A.x + B.x);
                float Xei = 0.5f * (A.y - B.y);
                float Xor = 0.5f * (A.y + B.y);
                float Xoi = -0.5f * (A.x - B.x);
                float2 w = cmul(wUs, make_float2(K16c[u], K16s[u])); // W_16384^{s+512u}
                float Xr = Xer + Xor * w.x - Xoi * w.y;
                float Xi = Xei + Xor * w.y + Xoi * w.x;
                float pw = Xr * Xr + Xi * Xi;
                acc[u] += __logf(fmaf(100.0f, pw, 1.0f));
            }
        }
    }
    // acc[u] belongs to bin s+512u -> re-coalesce through LDS once, then store.
    __syncthreads();                     // last frame's B-reads complete
    {
        float* fbuf = (float*)buf;
#pragma unroll
        for (int u = 0; u < 16; ++u) fbuf[s + 512 * u] = acc[u];
        __syncthreads();
#pragma unroll
        for (int u = 0; u < 16; ++u)
            partial[(size_t)blockIdx.x * NBINS + t + 512 * u] = fbuf[t + 512 * u];
    }

    // ---- split mode: blocks 4..7 compute frame 2048's residue-class FFTs --
    // Block 4+r computes F_r = FFT_2048(z[4n+r]) via GS [8,8,8,4];
    // 256 threads x 8 elems; LDS map phi2(p) = p + (p>>4).
    if (Fout != (float*)0 && blockIdx.x >= 4 && blockIdx.x < 8) {
        const int r = blockIdx.x - 4;
        __syncthreads();                 // exchange reads done; buf reusable
        const int baseS = 2048 * 8192 - 8192;
        const int phit2 = t + (t >> 4);
        // wr = e^{-i pi(8t+2r)/8192}; hann via W16 tables at uix = 2j;
        // odd sample via wro = wr*KD.
        float2 wr = make_float2(cospif((float)(8 * t + 2 * r) * (1.0f / 8192.0f)),
                                -sinpif((float)(8 * t + 2 * r) * (1.0f / 8192.0f)));
        float2 wro = cmul(wr, KD);
        if (t < 256) {   // pass 1: L=2048, elems n = t + 256j, w = W_2048^t
            float2 x[8];
#pragma unroll
            for (int j = 0; j < 8; ++j) {
                int e0 = baseS + 8 * t + 2 * r + 2048 * j;   // audio idx of 2s
                float a0 = audio[refl_idx(e0)];
                float a1 = audio[refl_idx(e0 + 1)];
                float c0 = 0.5f - 0.5f * (wr.x * W16C[2 * j] + wr.y * W16S[2 * j]);
                float c1 = 0.5f - 0.5f * (wro.x * W16C[2 * j] + wro.y * W16S[2 * j]);
                x[j] = make_float2(a0 * c0, a1 * c1);
            }
            float2 w = make_float2(cospif((float)t * (1.0f / 1024.0f)),
                                   -sinpif((float)t * (1.0f / 1024.0f)));
            r8(x, w);
#pragma unroll
            for (int j = 0; j < 8; ++j) buf[phit2 + 272 * j] = x[j];
        }
        __syncthreads();
        if (t < 256) {   // pass 2: L=256, B = t>>5, q = t&31
            const int q = t & 31;
            const int bs = 272 * (t >> 5) + q + (q >> 4);
            float2 x[8];
#pragma unroll
            for (int j = 0; j < 8; ++j) x[j] = buf[bs + 34 * j];
            float2 w = make_float2(cospif((float)q * (1.0f / 128.0f)),
                                   -sinpif((float)q * (1.0f / 128.0f)));
            r8(x, w);
#pragma unroll
            for (int j = 0; j < 8; ++j) buf[bs + 34 * j] = x[j];
        }
        __syncthreads();
        if (t < 256) {   // pass 3: L=32, B = t>>2, q = t&3
            const int q = t & 3;
            const int bs = 34 * (t >> 2) + q;
            float2 x[8];
#pragma unroll
            for (int j = 0; j < 8; ++j) x[j] = buf[bs + 4 * j + (j >> 2)];
            float2 w = make_float2(cospif((float)q * (1.0f / 16.0f)),
                                   -sinpif((float)q * (1.0f / 16.0f)));
            r8(x, w);
#pragma unroll
            for (int j = 0; j < 8; ++j) buf[bs + 4 * j + (j >> 2)] = x[j];
        }
        __syncthreads();
        if (t < 256) {   // pass 4: radix-4 on contiguous groups 2t, 2t+1
#pragma unroll
            for (int gg = 0; gg < 2; ++gg) {
                int g = 2 * t + gg;
                int bs = 4 * g + (g >> 2);
                float2 x0 = buf[bs], x1 = buf[bs + 1];
                float2 x2 = buf[bs + 2], x3 = buf[bs + 3];
                r4(x0, x1, x2, x3, ONE, ONE, ONE);
                buf[bs] = x0; buf[bs + 1] = x1; buf[bs + 2] = x2; buf[bs + 3] = x3;
            }
        }
        __syncthreads();
        if (t < 256) {   // store F_r[p] = buf[phi2(p)], p = t + 256j
            float2* fo = (float2*)Fout + r * 2048;
#pragma unroll
            for (int j = 0; j < 8; ++j) fo[t + 256 * j] = buf[phit2 + 272 * j];
        }
    }
}

// ---------------- Kernel B: parallel deterministic reduce -------------------
// float4 loads, order bit-identical to the verified scalar kernel. In split
// mode (F != 0), adds frame 2048's log-power per bin: X[k] = 4-term Horner
// over F_r[k mod 2048] with w = W_8192^k, then the standard rfft untangle +
// power + log (added LAST -> deterministic).
__global__ __launch_bounds__(128) void reduce_kernel(
        const float* __restrict__ partial, float* __restrict__ spec, int P,
        const float* __restrict__ F) {
    __shared__ float4 s[4][33];
    const int bin0 = blockIdx.x * 128;
    const int co = threadIdx.x & 31;
    const int g  = threadIdx.x >> 5;       // 0..3
    const int rows = P >> 2;               // P/4
    const int RS = NBINS / 4;              // float4 row stride
    const float4* base = (const float4*)(partial + (size_t)g * rows * NBINS + bin0) + co;
    float4 a0 = make_float4(0.f, 0.f, 0.f, 0.f);
    float4 a1 = make_float4(0.f, 0.f, 0.f, 0.f);
    int r = 0;
    for (; r + 16 <= rows; r += 16) {
        float4 l[16];
#pragma unroll
        for (int q = 0; q < 16; ++q) l[q] = base[(size_t)(r + q) * RS];
#pragma unroll
        for (int q = 0; q < 16; q += 2) {
            a0.x += l[q].x; a0.y += l[q].y; a0.z += l[q].z; a0.w += l[q].w;
            a1.x += l[q+1].x; a1.y += l[q+1].y; a1.z += l[q+1].z; a1.w += l[q+1].w;
        }
    }
    for (; r + 2 <= rows; r += 2) {
        float4 l0 = base[(size_t)r * RS];
        float4 l1 = base[(size_t)(r + 1) * RS];
        a0.x += l0.x; a0.y += l0.y; a0.z += l0.z; a0.w += l0.w;
        a1.x += l1.x; a1.y += l1.y; a1.z += l1.z; a1.w += l1.w;
    }
    for (; r < rows; ++r) {
        float4 l0 = base[(size_t)r * RS];
        a0.x += l0.x; a0.y += l0.y; a0.z += l0.z; a0.w += l0.w;
    }
    s[g][co] = make_float4(a0.x + a1.x, a0.y + a1.y, a0.z + a1.z, a0.w + a1.w);
    __syncthreads();
    if (threadIdx.x < 32) {
        float4 s0 = s[0][threadIdx.x], s1 = s[1][threadIdx.x];
        float4 s2 = s[2][threadIdx.x], s3 = s[3][threadIdx.x];
        float4 v = make_float4((s0.x + s1.x) + (s2.x + s3.x),
                               (s0.y + s1.y) + (s2.y + s3.y),
                               (s0.z + s1.z) + (s2.z + s3.z),
                               (s0.w + s1.w) + (s2.w + s3.w));
        if (F != (const float*)0) {
            const float2* Fb = (const float2*)F;   // 4 tables of 2048
            float* vv = &v.x;
#pragma unroll
            for (int c = 0; c < 4; ++c) {
                int b = bin0 + 4 * threadIdx.x + c;
                // X(b) via 4-term Horner
                int kh = posOf2048(b & 2047);
                float2 wk = make_float2(cospif((float)b * (1.0f / 4096.0f)),
                                        -sinpif((float)b * (1.0f / 4096.0f)));
                float2 Xk = Fb[6144 + kh];
                Xk = cmul(wk, Xk);
                Xk.x += Fb[4096 + kh].x; Xk.y += Fb[4096 + kh].y;
                Xk = cmul(wk, Xk);
                Xk.x += Fb[2048 + kh].x; Xk.y += Fb[2048 + kh].y;
                Xk = cmul(wk, Xk);
                Xk.x += Fb[kh].x; Xk.y += Fb[kh].y;
                // X(pb), pb = (8192-b) mod 8192
                int pb = (8192 - b) & 8191;
                int ph = posOf2048(pb & 2047);
                float2 wp = make_float2(cospif((float)pb * (1.0f / 4096.0f)),
                                        -sinpif((float)pb * (1.0f / 4096.0f)));
                float2 Xp = Fb[6144 + ph];
                Xp = cmul(wp, Xp);
                Xp.x += Fb[4096 + ph].x; Xp.y += Fb[4096 + ph].y;
                Xp = cmul(wp, Xp);
                Xp.x += Fb[2048 + ph].x; Xp.y += Fb[2048 + ph].y;
                Xp = cmul(wp, Xp);
                Xp.x += Fb[ph].x; Xp.y += Fb[ph].y;
                // rfft untangle + power + log
                float Xer = 0.5f * (Xk.x + Xp.x);
                float Xei = 0.5f * (Xk.y - Xp.y);
                float Xor = 0.5f * (Xk.y + Xp.y);
                float Xoi = -0.5f * (Xk.x - Xp.x);
                float2 wu = make_float2(cospif((float)b * (1.0f / 8192.0f)),
                                        -sinpif((float)b * (1.0f / 8192.0f)));
                float Xr = Xer + Xor * wu.x - Xoi * wu.y;
                float Xi = Xei + Xor * wu.y + Xoi * wu.x;
                float pw = Xr * Xr + Xi * Xi;
                vv[c] += __logf(fmaf(100.0f, pw, 1.0f));
            }
        }
        if (!(blockIdx.x == 63 && threadIdx.x == 31))   // keep counter cell
            ((float4*)(spec + bin0))[threadIdx.x] = v;
    }
}

// ---------------- Kernel C: spline + smooth + relu, then the LAST-arriving
// block runs the comb+argmax inline (no-spin last-block pattern). 33 blocks.
__global__ __launch_bounds__(256) void cent_spline_comb_kernel(
        const float* __restrict__ spec, const float* __restrict__ wsm,
        const float* __restrict__ wdet, float* __restrict__ filt,
        float* __restrict__ out) {
    __shared__ float ys[768];
    __shared__ float dps[704];
    __shared__ float Ms[640];
    __shared__ float cs[356];
    __shared__ float wsm_s[101];
    __shared__ float invden_s[64];
    const int tid = threadIdx.x;
    const int j0 = blockIdx.x * 256;
    const float h = 22050.0f / 16384.0f;
    const float hh = h * h;

    if (tid == 0) {
        double v = 0.25;
        invden_s[0] = 0.25f;
        for (int i = 1; i < 64; ++i) { v = 1.0 / (4.0 - v); invden_s[i] = (float)v; }
    }
    for (int r = tid; r < 101; r += 256) wsm_s[r] = wsm[r];

    const int jLo = max(j0 - 50, 0);
    const int jHi = min(j0 + 305, NQ - 1);
    const float xqLo = (float)(440.0 * exp2(((double)jLo * 0.01 - 45.0) * (1.0 / 12.0)));
    const float xqHi = (float)(440.0 * exp2(((double)jHi * 0.01 - 45.0) * (1.0 / 12.0)));
    const int iLo = min(max((int)floorf(xqLo / h), 0), 8190);
    const int iHi = min(max((int)floorf(xqHi / h), 0), 8190);
    const int pLo = max(iLo - 2, 0);
    const int pHi = min(iHi - 1, MUNK - 1);
    const int bHi = min(pHi + 64, MUNK - 1);
    const int yLo = max(pLo - 64, 0);
    const int yHi = bHi + 3;
    const int ny  = yHi - yLo + 1;

    for (int k = tid; k < ny; k += 256) ys[k] = spec[yLo + k];
    __syncthreads();
    const float cst = invden_s[63];   // 2 - sqrt(3)

    {
        const int nch = (bHi - pLo + 32) >> 5;
        if (tid < nch) {
            const int s = pLo + (tid << 5);
            const int e = min(s + 31, bHi);
            const int ws = max(s - 64, 0);
            float dprev = 0.0f;
            for (int i = ws; i <= e; ++i) {
                float d1 = (ys[i + 1 - yLo] - 2.0f * ys[i + 2 - yLo]
                            + ys[i + 3 - yLo]) / hh;
                float r = 6.0f * d1;
                if (i == 0) r -= (ys[0] - 2.0f * ys[1] + ys[2]) / hh;
                float val = (i == 0) ? r : (r - dprev);
                float dpv = val * ((i < 64) ? invden_s[i] : cst);
                if (i >= s) dps[i - pLo] = dpv;
                dprev = dpv;
            }
        }
    }
    __syncthreads();
    {
        const int nch = (pHi - pLo + 32) >> 5;
        if (tid < nch) {
            const int s = pLo + (tid << 5);
            const int e = min(s + 31, pHi);
            const int ws2 = min(e + 64, bHi);
            float xnext = 0.0f;
            for (int i = ws2; i >= s; --i) {
                float cp = (i == MUNK - 1) ? 0.0f : ((i < 64) ? invden_s[i] : cst);
                float xv = dps[i - pLo] - cp * xnext;
                if (i <= e) Ms[2 + i - iLo] = xv;
                xnext = xv;
            }
        }
    }
    __syncthreads();
    for (int r = tid; r < 356; r += 256) {
        int j = j0 - 50 + r;
        float v = 0.0f;
        if (j >= 0 && j < NQ) {
            double e = ((double)j * 0.01 - 45.0) * (1.0 / 12.0);
            float xq = (float)(440.0 * exp2(e));
            int i = min(max((int)floorf(xq / h), 0), 8190);
            float tt = xq - (float)i * h;
            float uu = h - tt;
            float Mi = Ms[i - iLo], Mi1 = Ms[i + 1 - iLo];
            float yi = ys[i - yLo], yi1 = ys[i + 1 - yLo];
            v = (Mi * uu * uu * uu + Mi1 * tt * tt * tt) / (6.0f * h)
              + (yi - Mi * hh / 6.0f) * uu / h
              + (yi1 - Mi1 * hh / 6.0f) * tt / h;
        }
        cs[r] = v;
    }
    __syncthreads();
    int j = j0 + tid;
    if (j < NQ) {
        float s = 0.0f;
        for (int m = 0; m < 101; ++m) s = fmaf(wsm_s[m], cs[tid + 100 - m], s);
        float fv = cs[tid + 50] - s;
        filt[j] = fv > 0.0f ? fv : 0.0f;
    }
    __syncthreads();

    // ---- last-arriving block runs comb+argmax (deterministic) ----
    __shared__ unsigned int lastflag;
    unsigned int* cnt = (unsigned int*)(spec + 8188);
    __threadfence();
    if (tid == 0) {
        unsigned int prev =
            __hip_atomic_fetch_add(cnt, 1u, __ATOMIC_ACQ_REL, __HIP_MEMORY_SCOPE_AGENT);
        lastflag = (prev == 32u) ? 1u : 0u;
    }
    __syncthreads();
    if (!lastflag) return;
    __threadfence();

    {
        __shared__ float fs[NQ];
        __shared__ float wd[84];
        __shared__ float sc[100];
        const int t = tid;
        for (int k = t; k < NQ; k += 256) fs[k] = filt[k];
        if (t < 84) wd[t] = wdet[t];
        __syncthreads();
        if (t < 100) {
            float s = 0.0f;
            for (int k = 0; k < 84; ++k) {
                int ix = t - 50 + 100 * k;
                if (ix >= 0) s = fmaf(wd[k], fs[ix], s);
            }
            sc[t] = s;
            out[1 + t] = s;
        }
        __syncthreads();
        if (t < 64) {    // wave argmax, first-max tie-break
            float v = (t < 100) ? sc[t] : -1e30f;
            int i = t;
            int t2 = t + 64;
            float v2 = (t2 < 100) ? sc[t2] : -1e30f;
            if (v2 > v) { v = v2; i = t2; }
#pragma unroll
            for (int off = 32; off; off >>= 1) {
                float ov = __shfl_xor(v, off, 64);
                int   oi = __shfl_xor(i, off, 64);
                if (ov > v || (ov == v && oi < i)) { v = ov; i = oi; }
            }
            if (t == 0) out[0] = (float)(i - 50);
        }
    }
}

extern "C" void kernel_launch(void* const* d_in, const int* in_sizes, int n_in,
                              void* d_out, int out_size, void* d_ws, size_t ws_size,
                              hipStream_t stream) {
    const float* audio = (const float*)d_in[0];
    const float* wsm   = (const float*)d_in[1];
    const float* wdet  = (const float*)d_in[2];
    float* out = (float*)d_out;
    float* ws  = (float*)d_ws;

    long cap = (long)(ws_size / sizeof(float) / NBINS) - 1;
    int P = (int)(cap < 4 ? 4 : (cap > 512 ? 512 : cap));
    P &= ~3;                               // multiple of 4 for the reduce
    float* spec    = ws;
    float* partial = ws + NBINS;           // P rows of 8192
    float* filt    = ws + 2 * NBINS;       // reuses partial rows (dead after reduce)

    // split mode: needs exactly-4-frames-per-block (P==512) and 2 spare rows
    // beyond partial for the 4 F tables (4 x 2048 cfloat = 64 KB).
    int doSplit = (P == 512 && cap >= (long)P + 3) ? 1 : 0;
    float* F = doSplit ? (ws + (size_t)(1 + P) * NBINS) : (float*)0;
    int fmax = doSplit ? 2048 : T_FRAMES;

    hipLaunchKernelGGL(fft_pow_kernel, dim3(P), dim3(512), 0, stream,
                       audio, partial, P, fmax, F);
    hipLaunchKernelGGL(reduce_kernel, dim3(64), dim3(128), 0, stream,
                       partial, spec, P, F);
    hipLaunchKernelGGL(cent_spline_comb_kernel, dim3(33), dim3(256), 0, stream,
                       spec, wsm, wdet, filt, out);
}

// Round 12
// 113.127 us; speedup vs baseline: 1.0058x; 1.0058x over previous
//
#include <hip/hip_runtime.h>
#include <math.h>

#define NBINS   8192
#define L_AUDIO 16777216
#define T_FRAMES 2049
#define NQ      8400
#define MUNK    8188

__device__ __forceinline__ int refl_idx(int m) {
    if (m < 0) m = -m;
    if (m >= L_AUDIO) m = 2 * L_AUDIO - 2 - m;
    return m;
}
__device__ __forceinline__ float2 cmul(float2 a, float2 b) {
    return make_float2(fmaf(a.x, b.x, -a.y * b.y), fmaf(a.x, b.y, a.y * b.x));
}
__device__ __forceinline__ float2 csq(float2 a) {
    return make_float2(fmaf(a.x, a.x, -a.y * a.y), 2.0f * a.x * a.y);
}
// Gentleman-Sande radix-4: w_r = W_L^{r*q0}; output r stays at q0 + r*L/4.
// With unit twiddles (q0=0), slot r holds bin-residue r (identity map).
__device__ __forceinline__ void r4(float2& x0, float2& x1, float2& x2, float2& x3,
                                   float2 w1, float2 w2, float2 w3) {
    float2 t0 = make_float2(x0.x + x2.x, x0.y + x2.y);
    float2 t1 = make_float2(x1.x + x3.x, x1.y + x3.y);
    float2 t2 = make_float2(x0.x - x2.x, x0.y - x2.y);
    float2 t3 = make_float2(x1.x - x3.x, x1.y - x3.y);
    float2 b1 = make_float2(t2.x + t3.y, t2.y - t3.x);   // t2 - i*t3
    float2 b3 = make_float2(t2.x - t3.y, t2.y + t3.x);   // t2 + i*t3
    x0 = make_float2(t0.x + t1.x, t0.y + t1.y);
    x1 = cmul(w1, b1);
    x2 = cmul(w2, make_float2(t0.x - t1.x, t0.y - t1.y));
    x3 = cmul(w3, b3);
}
// radix-8 on 8 elems at q0 + j*L/8; all twiddles derived from w = W_L^{q0}.
// Output slot j holds bin-residue rho(j) = (j&1)*4 + (j>>1)  [derived r8 map].
__device__ __forceinline__ void r8(float2 x[8], float2 w) {
    const float c = 0.70710678118654752f;
    float2 w2 = csq(w), w3 = cmul(w, w2), w4 = csq(w2);
    r4(x[0], x[2], x[4], x[6], w, w2, w3);
    float2 wE   = make_float2(c * (w.x + w.y),  c * (w.y - w.x));     // w*e^{-i pi/4}
    float2 w2E2 = make_float2(w2.y, -w2.x);                           // w2*(-i)
    float2 w3E3 = make_float2(c * (w3.y - w3.x), -c * (w3.x + w3.y)); // w3*e^{-i3pi/4}
    r4(x[1], x[3], x[5], x[7], wE, w2E2, w3E3);
#pragma unroll
    for (int r = 0; r < 4; ++r) {
        float2 a = x[2 * r], b = x[2 * r + 1];
        x[2 * r]     = make_float2(a.x + b.x, a.y + b.y);
        float2 d     = make_float2(a.x - b.x, a.y - b.y);
        x[2 * r + 1] = cmul(w4, d);
    }
}
// inverse of rho: slot index holding residue r in an r8 output group
__device__ __forceinline__ int jof(int r) {
    return ((r >> 1) & 1) * 4 + (r & 1) * 2 + (r >> 2);
}
// position of logical bin m in the 2048-pt [8,8,8,4] GS chain output
// (final radix-4 has unit twiddles -> identity slot map for the top digit)
__device__ __forceinline__ int posOf2048(int m) {
    return 256 * jof(m & 7) + 32 * jof((m >> 3) & 7)
         + 4 * jof((m >> 6) & 7) + (m >> 9);
}

// ---------------- Kernel A: 512 threads, in-place 8192-pt complex FFT as
// 3x radix-8 + fused (radix-8 x2 + radix-2 in regs); window+pack fused into
// pass 1. Body = round-10 (r11's register-untangle reverted: +3us, longer
// live ranges beat the 16 saved LDS reads). Split mode (fmax==2048): every
// block does exactly 4 frames; frame 2048 via blocks 4..7 as 4 decimated
// 2048-pt FFTs. Round-12: s_setprio(1) around the pure-VALU butterfly
// chains — the CU's TWO co-resident blocks are unsynchronized (T5/m191
// regime: independent wave-groups at different phases), so a computing
// wave gets priority over the other block's load-issuing waves. ----------
__global__ __launch_bounds__(512, 2) void fft_pow_kernel(
        const float* __restrict__ audio, float* __restrict__ partial, int P,
        int fmax, float* __restrict__ Fout) {
    __shared__ float2 buf[8718];   // phi(p) = p + (p>>4) + (p>>9), max 8717
    const int t = threadIdx.x;

    if (blockIdx.x == 0 && t == 0) {   // counter lives at spec[8188]
        unsigned int* cz = (unsigned int*)(partial - 4);
        cz[0] = 0u;
    }

    const int phit  = t + (t >> 4);                         // phi(t), t < 512
    const int q2    = t & 127;
    const int base2 = 1090 * (t >> 7) + q2 + (q2 >> 4);     // pass2 base
    const int base3 = 136 * (t >> 4) + ((t >> 4) >> 2) + (t & 15);
    const int base4 = 17 * t + (t >> 5);
    const int tp    = (512 - t) & 511;
    const int PBt = (t & 3) * 2048 + ((t >> 2) & 1) * 1024 + ((t >> 3) & 3) * 256
                  + ((t >> 5) & 1) * 128 + ((t >> 6) & 3) * 32 + ((t >> 8) & 1) * 16;
    const int PBp = (tp & 3) * 2048 + ((tp >> 2) & 1) * 1024 + ((tp >> 3) & 3) * 256
                  + ((tp >> 5) & 1) * 128 + ((tp >> 6) & 3) * 32 + ((tp >> 8) & 1) * 16;
    const int ubA = PBt + (PBt >> 4) + (PBt >> 9);
    const int ubB = PBp + (PBp >> 4) + (PBp >> 9);

    const float2 ONE = make_float2(1.0f, 0.0f);
    const float2 K8  = make_float2(0.92387953251128674f, -0.38268343236508977f); // e^{-i pi/8}
    const float2 KD  = make_float2(0.99999992646574f, -0.00038349518757f);       // e^{-i pi/8192}
    float2 wU  = make_float2(cospif((float)t * (1.0f / 8192.0f)),
                             -sinpif((float)t * (1.0f / 8192.0f)));  // W_16384^t
    float2 w1  = csq(wU);                                            // W_8192^t
    float2 wodd = cmul(w1, KD);                                      // e^{-i pi(2t+1)/8192}
    float2 w2t = make_float2(cospif((float)q2 * (1.0f / 512.0f)),
                             -sinpif((float)q2 * (1.0f / 512.0f)));  // W_1024^(t&127)
    float2 w3t = make_float2(cospif((float)(t & 15) * (1.0f / 64.0f)),
                             -sinpif((float)(t & 15) * (1.0f / 64.0f))); // W_128^(t&15)
    const float K16c[16] = {1.0f, 0.98078528040323044f, 0.92387953251128674f,
        0.83146961230254524f, 0.70710678118654752f, 0.55557023301960222f,
        0.38268343236508977f, 0.19509032201612825f, 0.0f, -0.19509032201612825f,
        -0.38268343236508977f, -0.55557023301960222f, -0.70710678118654752f,
        -0.83146961230254524f, -0.92387953251128674f, -0.98078528040323044f};
    const float K16s[16] = {0.0f, -0.19509032201612825f, -0.38268343236508977f,
        -0.55557023301960222f, -0.70710678118654752f, -0.83146961230254524f,
        -0.92387953251128674f, -0.98078528040323044f, -1.0f, -0.98078528040323044f,
        -0.92387953251128674f, -0.83146961230254524f, -0.70710678118654752f,
        -0.55557023301960222f, -0.38268343236508977f, -0.19509032201612825f};
    // window rotation: cos/sin(pi u/8), u in [0,16)
    const float W16C[16] = {1.0f, 0.92387953251128674f, 0.70710678118654752f,
        0.38268343236508977f, 0.0f, -0.38268343236508977f, -0.70710678118654752f,
        -0.92387953251128674f, -1.0f, -0.92387953251128674f, -0.70710678118654752f,
        -0.38268343236508977f, 0.0f, 0.38268343236508977f, 0.70710678118654752f,
        0.92387953251128674f};
    const float W16S[16] = {0.0f, 0.38268343236508977f, 0.70710678118654752f,
        0.92387953251128674f, 1.0f, 0.92387953251128674f, 0.70710678118654752f,
        0.38268343236508977f, 0.0f, -0.38268343236508977f, -0.70710678118654752f,
        -0.92387953251128674f, -1.0f, -0.92387953251128674f, -0.70710678118654752f,
        -0.38268343236508977f};

    float acc[16];
#pragma unroll
    for (int u = 0; u < 16; ++u) acc[u] = 0.0f;

    for (int f = blockIdx.x; f < fmax; f += P) {
        __syncthreads();   // previous frame's untangle reads vs pass-1 writes
        // ---- pass 1 (fused window+pack): L=8192, q0 = t + 512g ----
        const bool interior = (f != 0) && (f != T_FRAMES - 1);
        const float2* au2 = (const float2*)audio + 4096 * (f - 1);
        const int baseS = f * 8192 - 8192;
#pragma unroll 1
        for (int g = 0; g < 2; ++g) {
            float2 x[8];
            if (interior) {
#pragma unroll
                for (int j = 0; j < 8; ++j) {
                    int idx = t + 512 * g + 1024 * j;
                    float2 p = au2[idx];
                    const int uix = g + 2 * j;
                    float c0 = 0.5f - 0.5f * (w1.x * W16C[uix] + w1.y * W16S[uix]);
                    float c1 = 0.5f - 0.5f * (wodd.x * W16C[uix] + wodd.y * W16S[uix]);
                    x[j] = make_float2(p.x * c0, p.y * c1);
                }
            } else {
#pragma unroll
                for (int j = 0; j < 8; ++j) {
                    int idx = t + 512 * g + 1024 * j;
                    float a0 = audio[refl_idx(baseS + 2 * idx)];
                    float a1 = audio[refl_idx(baseS + 2 * idx + 1)];
                    const int uix = g + 2 * j;
                    float c0 = 0.5f - 0.5f * (w1.x * W16C[uix] + w1.y * W16S[uix]);
                    float c1 = 0.5f - 0.5f * (wodd.x * W16C[uix] + wodd.y * W16S[uix]);
                    x[j] = make_float2(a0 * c0, a1 * c1);
                }
            }
            float2 w = g ? cmul(w1, K8) : w1;
            __builtin_amdgcn_s_setprio(1);
            r8(x, w);
            __builtin_amdgcn_s_setprio(0);
#pragma unroll
            for (int j = 0; j < 8; ++j) buf[phit + 545 * g + 1090 * j] = x[j];
        }
        __syncthreads();
        // pass 2: L=1024, B = (t>>7)+4g, q0 = t&127, stride 128
#pragma unroll 1
        for (int g = 0; g < 2; ++g) {
            float2 x[8];
            const int bs = base2 + 4360 * g;
#pragma unroll
            for (int j = 0; j < 8; ++j) x[j] = buf[bs + 136 * j + (j >> 2)];
            __builtin_amdgcn_s_setprio(1);
            r8(x, w2t);
            __builtin_amdgcn_s_setprio(0);
#pragma unroll
            for (int j = 0; j < 8; ++j) buf[bs + 136 * j + (j >> 2)] = x[j];
        }
        __syncthreads();
        // pass 3: L=128, B = (t>>4)+32g, q0 = t&15, stride 16
#pragma unroll 1
        for (int g = 0; g < 2; ++g) {
            float2 x[8];
            const int bs = base3 + 4360 * g;
#pragma unroll
            for (int j = 0; j < 8; ++j) x[j] = buf[bs + 17 * j];
            __builtin_amdgcn_s_setprio(1);
            r8(x, w3t);
            __builtin_amdgcn_s_setprio(0);
#pragma unroll
            for (int j = 0; j < 8; ++j) buf[bs + 17 * j] = x[j];
        }
        __syncthreads();
        // pass 4+5 fused
        {
            float2 a[8], x[8];
#pragma unroll
            for (int j = 0; j < 8; ++j) a[j] = buf[base4 + 2 * j];
#pragma unroll
            for (int j = 0; j < 8; ++j) x[j] = buf[base4 + 1 + 2 * j];
            __builtin_amdgcn_s_setprio(1);
            r8(a, ONE);
            r8(x, K8);
            __builtin_amdgcn_s_setprio(0);
#pragma unroll
            for (int j = 0; j < 8; ++j) {
                buf[base4 + 2 * j]     = make_float2(a[j].x + x[j].x, a[j].y + x[j].y);
                buf[base4 + 2 * j + 1] = make_float2(a[j].x - x[j].x, a[j].y - x[j].y);
            }
        }
        __syncthreads();
        // untangle real FFT at digit-reversed positions, power, log
#pragma unroll
        for (int u = 0; u < 16; ++u) {
            const int off = (u & 3) * 4 + ((u >> 2) & 1) * 2 + (u >> 3);
            int u2 = t ? (15 - u) : ((16 - u) & 15);
            int off2 = (u2 & 3) * 4 + ((u2 >> 2) & 1) * 2 + (u2 >> 3);
            float2 A = buf[ubA + off];
            float2 B = buf[ubB + off2];
            float Xer = 0.5f * (A.x + B.x);
            float Xei = 0.5f * (A.y - B.y);
            float Xor = 0.5f * (A.y + B.y);
            float Xoi = -0.5f * (A.x - B.x);
            float2 w = cmul(wU, make_float2(K16c[u], K16s[u]));  // W_16384^{t+512u}
            float Xr = Xer + Xor * w.x - Xoi * w.y;
            float Xi = Xei + Xor * w.y + Xoi * w.x;
            float pw = Xr * Xr + Xi * Xi;
            acc[u] += __logf(fmaf(100.0f, pw, 1.0f));
        }
    }
#pragma unroll
    for (int u = 0; u < 16; ++u)
        partial[(size_t)blockIdx.x * NBINS + t + 512 * u] = acc[u];

    // ---- split mode: blocks 4..7 compute frame 2048's residue-class FFTs --
    // Block 4+r computes F_r = FFT_2048(z[4n+r]) via GS [8,8,8,4];
    // 256 threads x 8 elems; LDS map phi2(p) = p + (p>>4).
    if (Fout != (float*)0 && blockIdx.x >= 4 && blockIdx.x < 8) {
        const int r = blockIdx.x - 4;
        __syncthreads();                 // main loop's untangle reads done
        const int baseS = 2048 * 8192 - 8192;
        const int phit2 = t + (t >> 4);
        // wr = e^{-i pi(8t+2r)/8192}; hann via W16 tables at uix = 2j;
        // odd sample via wro = wr*KD.
        float2 wr = make_float2(cospif((float)(8 * t + 2 * r) * (1.0f / 8192.0f)),
                                -sinpif((float)(8 * t + 2 * r) * (1.0f / 8192.0f)));
        float2 wro = cmul(wr, KD);
        if (t < 256) {   // pass 1: L=2048, elems n = t + 256j, w = W_2048^t
            float2 x[8];
#pragma unroll
            for (int j = 0; j < 8; ++j) {
                int e0 = baseS + 8 * t + 2 * r + 2048 * j;   // audio idx of 2s
                float a0 = audio[refl_idx(e0)];
                float a1 = audio[refl_idx(e0 + 1)];
                float c0 = 0.5f - 0.5f * (wr.x * W16C[2 * j] + wr.y * W16S[2 * j]);
                float c1 = 0.5f - 0.5f * (wro.x * W16C[2 * j] + wro.y * W16S[2 * j]);
                x[j] = make_float2(a0 * c0, a1 * c1);
            }
            float2 w = make_float2(cospif((float)t * (1.0f / 1024.0f)),
                                   -sinpif((float)t * (1.0f / 1024.0f)));
            r8(x, w);
#pragma unroll
            for (int j = 0; j < 8; ++j) buf[phit2 + 272 * j] = x[j];
        }
        __syncthreads();
        if (t < 256) {   // pass 2: L=256, B = t>>5, q = t&31
            const int q = t & 31;
            const int bs = 272 * (t >> 5) + q + (q >> 4);
            float2 x[8];
#pragma unroll
            for (int j = 0; j < 8; ++j) x[j] = buf[bs + 34 * j];
            float2 w = make_float2(cospif((float)q * (1.0f / 128.0f)),
                                   -sinpif((float)q * (1.0f / 128.0f)));
            r8(x, w);
#pragma unroll
            for (int j = 0; j < 8; ++j) buf[bs + 34 * j] = x[j];
        }
        __syncthreads();
        if (t < 256) {   // pass 3: L=32, B = t>>2, q = t&3
            const int q = t & 3;
            const int bs = 34 * (t >> 2) + q;
            float2 x[8];
#pragma unroll
            for (int j = 0; j < 8; ++j) x[j] = buf[bs + 4 * j + (j >> 2)];
            float2 w = make_float2(cospif((float)q * (1.0f / 16.0f)),
                                   -sinpif((float)q * (1.0f / 16.0f)));
            r8(x, w);
#pragma unroll
            for (int j = 0; j < 8; ++j) buf[bs + 4 * j + (j >> 2)] = x[j];
        }
        __syncthreads();
        if (t < 256) {   // pass 4: radix-4 on contiguous groups 2t, 2t+1
#pragma unroll
            for (int gg = 0; gg < 2; ++gg) {
                int g = 2 * t + gg;
                int bs = 4 * g + (g >> 2);
                float2 x0 = buf[bs], x1 = buf[bs + 1];
                float2 x2 = buf[bs + 2], x3 = buf[bs + 3];
                r4(x0, x1, x2, x3, ONE, ONE, ONE);
                buf[bs] = x0; buf[bs + 1] = x1; buf[bs + 2] = x2; buf[bs + 3] = x3;
            }
        }
        __syncthreads();
        if (t < 256) {   // store F_r[p] = buf[phi2(p)], p = t + 256j
            float2* fo = (float2*)Fout + r * 2048;
#pragma unroll
            for (int j = 0; j < 8; ++j) fo[t + 256 * j] = buf[phit2 + 272 * j];
        }
    }
}

// ---------------- Kernel B: parallel deterministic reduce -------------------
// float4 loads, order bit-identical to the verified scalar kernel. In split
// mode (F != 0), adds frame 2048's log-power per bin: X[k] = 4-term Horner
// over F_r[k mod 2048] with w = W_8192^k, then the standard rfft untangle +
// power + log (added LAST -> deterministic).
__global__ __launch_bounds__(128) void reduce_kernel(
        const float* __restrict__ partial, float* __restrict__ spec, int P,
        const float* __restrict__ F) {
    __shared__ float4 s[4][33];
    const int bin0 = blockIdx.x * 128;
    const int co = threadIdx.x & 31;
    const int g  = threadIdx.x >> 5;       // 0..3
    const int rows = P >> 2;               // P/4
    const int RS = NBINS / 4;              // float4 row stride
    const float4* base = (const float4*)(partial + (size_t)g * rows * NBINS + bin0) + co;
    float4 a0 = make_float4(0.f, 0.f, 0.f, 0.f);
    float4 a1 = make_float4(0.f, 0.f, 0.f, 0.f);
    int r = 0;
    for (; r + 16 <= rows; r += 16) {
        float4 l[16];
#pragma unroll
        for (int q = 0; q < 16; ++q) l[q] = base[(size_t)(r + q) * RS];
#pragma unroll
        for (int q = 0; q < 16; q += 2) {
            a0.x += l[q].x; a0.y += l[q].y; a0.z += l[q].z; a0.w += l[q].w;
            a1.x += l[q+1].x; a1.y += l[q+1].y; a1.z += l[q+1].z; a1.w += l[q+1].w;
        }
    }
    for (; r + 2 <= rows; r += 2) {
        float4 l0 = base[(size_t)r * RS];
        float4 l1 = base[(size_t)(r + 1) * RS];
        a0.x += l0.x; a0.y += l0.y; a0.z += l0.z; a0.w += l0.w;
        a1.x += l1.x; a1.y += l1.y; a1.z += l1.z; a1.w += l1.w;
    }
    for (; r < rows; ++r) {
        float4 l0 = base[(size_t)r * RS];
        a0.x += l0.x; a0.y += l0.y; a0.z += l0.z; a0.w += l0.w;
    }
    s[g][co] = make_float4(a0.x + a1.x, a0.y + a1.y, a0.z + a1.z, a0.w + a1.w);
    __syncthreads();
    if (threadIdx.x < 32) {
        float4 s0 = s[0][threadIdx.x], s1 = s[1][threadIdx.x];
        float4 s2 = s[2][threadIdx.x], s3 = s[3][threadIdx.x];
        float4 v = make_float4((s0.x + s1.x) + (s2.x + s3.x),
                               (s0.y + s1.y) + (s2.y + s3.y),
                               (s0.z + s1.z) + (s2.z + s3.z),
                               (s0.w + s1.w) + (s2.w + s3.w));
        if (F != (const float*)0) {
            const float2* Fb = (const float2*)F;   // 4 tables of 2048
            float* vv = &v.x;
#pragma unroll
            for (int c = 0; c < 4; ++c) {
                int b = bin0 + 4 * threadIdx.x + c;
                // X(b) via 4-term Horner
                int kh = posOf2048(b & 2047);
                float2 wk = make_float2(cospif((float)b * (1.0f / 4096.0f)),
                                        -sinpif((float)b * (1.0f / 4096.0f)));
                float2 Xk = Fb[6144 + kh];
                Xk = cmul(wk, Xk);
                Xk.x += Fb[4096 + kh].x; Xk.y += Fb[4096 + kh].y;
                Xk = cmul(wk, Xk);
                Xk.x += Fb[2048 + kh].x; Xk.y += Fb[2048 + kh].y;
                Xk = cmul(wk, Xk);
                Xk.x += Fb[kh].x; Xk.y += Fb[kh].y;
                // X(pb), pb = (8192-b) mod 8192
                int pb = (8192 - b) & 8191;
                int ph = posOf2048(pb & 2047);
                float2 wp = make_float2(cospif((float)pb * (1.0f / 4096.0f)),
                                        -sinpif((float)pb * (1.0f / 4096.0f)));
                float2 Xp = Fb[6144 + ph];
                Xp = cmul(wp, Xp);
                Xp.x += Fb[4096 + ph].x; Xp.y += Fb[4096 + ph].y;
                Xp = cmul(wp, Xp);
                Xp.x += Fb[2048 + ph].x; Xp.y += Fb[2048 + ph].y;
                Xp = cmul(wp, Xp);
                Xp.x += Fb[ph].x; Xp.y += Fb[ph].y;
                // rfft untangle + power + log
                float Xer = 0.5f * (Xk.x + Xp.x);
                float Xei = 0.5f * (Xk.y - Xp.y);
                float Xor = 0.5f * (Xk.y + Xp.y);
                float Xoi = -0.5f * (Xk.x - Xp.x);
                float2 wu = make_float2(cospif((float)b * (1.0f / 8192.0f)),
                                        -sinpif((float)b * (1.0f / 8192.0f)));
                float Xr = Xer + Xor * wu.x - Xoi * wu.y;
                float Xi = Xei + Xor * wu.y + Xoi * wu.x;
                float pw = Xr * Xr + Xi * Xi;
                vv[c] += __logf(fmaf(100.0f, pw, 1.0f));
            }
        }
        if (!(blockIdx.x == 63 && threadIdx.x == 31))   // keep counter cell
            ((float4*)(spec + bin0))[threadIdx.x] = v;
    }
}

// ---------------- Kernel C: spline + smooth + relu, then the LAST-arriving
// block runs the comb+argmax inline (no-spin last-block pattern). 33 blocks.
__global__ __launch_bounds__(256) void cent_spline_comb_kernel(
        const float* __restrict__ spec, const float* __restrict__ wsm,
        const float* __restrict__ wdet, float* __restrict__ filt,
        float* __restrict__ out) {
    __shared__ float ys[768];
    __shared__ float dps[704];
    __shared__ float Ms[640];
    __shared__ float cs[356];
    __shared__ float wsm_s[101];
    __shared__ float invden_s[64];
    const int tid = threadIdx.x;
    const int j0 = blockIdx.x * 256;
    const float h = 22050.0f / 16384.0f;
    const float hh = h * h;

    if (tid == 0) {
        double v = 0.25;
        invden_s[0] = 0.25f;
        for (int i = 1; i < 64; ++i) { v = 1.0 / (4.0 - v); invden_s[i] = (float)v; }
    }
    for (int r = tid; r < 101; r += 256) wsm_s[r] = wsm[r];

    const int jLo = max(j0 - 50, 0);
    const int jHi = min(j0 + 305, NQ - 1);
    const float xqLo = (float)(440.0 * exp2(((double)jLo * 0.01 - 45.0) * (1.0 / 12.0)));
    const float xqHi = (float)(440.0 * exp2(((double)jHi * 0.01 - 45.0) * (1.0 / 12.0)));
    const int iLo = min(max((int)floorf(xqLo / h), 0), 8190);
    const int iHi = min(max((int)floorf(xqHi / h), 0), 8190);
    const int pLo = max(iLo - 2, 0);
    const int pHi = min(iHi - 1, MUNK - 1);
    const int bHi = min(pHi + 64, MUNK - 1);
    const int yLo = max(pLo - 64, 0);
    const int yHi = bHi + 3;
    const int ny  = yHi - yLo + 1;

    for (int k = tid; k < ny; k += 256) ys[k] = spec[yLo + k];
    __syncthreads();
    const float cst = invden_s[63];   // 2 - sqrt(3)

    {
        const int nch = (bHi - pLo + 32) >> 5;
        if (tid < nch) {
            const int s = pLo + (tid << 5);
            const int e = min(s + 31, bHi);
            const int ws = max(s - 64, 0);
            float dprev = 0.0f;
            for (int i = ws; i <= e; ++i) {
                float d1 = (ys[i + 1 - yLo] - 2.0f * ys[i + 2 - yLo]
                            + ys[i + 3 - yLo]) / hh;
                float r = 6.0f * d1;
                if (i == 0) r -= (ys[0] - 2.0f * ys[1] + ys[2]) / hh;
                float val = (i == 0) ? r : (r - dprev);
                float dpv = val * ((i < 64) ? invden_s[i] : cst);
                if (i >= s) dps[i - pLo] = dpv;
                dprev = dpv;
            }
        }
    }
    __syncthreads();
    {
        const int nch = (pHi - pLo + 32) >> 5;
        if (tid < nch) {
            const int s = pLo + (tid << 5);
            const int e = min(s + 31, pHi);
            const int ws2 = min(e + 64, bHi);
            float xnext = 0.0f;
            for (int i = ws2; i >= s; --i) {
                float cp = (i == MUNK - 1) ? 0.0f : ((i < 64) ? invden_s[i] : cst);
                float xv = dps[i - pLo] - cp * xnext;
                if (i <= e) Ms[2 + i - iLo] = xv;
                xnext = xv;
            }
        }
    }
    __syncthreads();
    for (int r = tid; r < 356; r += 256) {
        int j = j0 - 50 + r;
        float v = 0.0f;
        if (j >= 0 && j < NQ) {
            double e = ((double)j * 0.01 - 45.0) * (1.0 / 12.0);
            float xq = (float)(440.0 * exp2(e));
            int i = min(max((int)floorf(xq / h), 0), 8190);
            float tt = xq - (float)i * h;
            float uu = h - tt;
            float Mi = Ms[i - iLo], Mi1 = Ms[i + 1 - iLo];
            float yi = ys[i - yLo], yi1 = ys[i + 1 - yLo];
            v = (Mi * uu * uu * uu + Mi1 * tt * tt * tt) / (6.0f * h)
              + (yi - Mi * hh / 6.0f) * uu / h
              + (yi1 - Mi1 * hh / 6.0f) * tt / h;
        }
        cs[r] = v;
    }
    __syncthreads();
    int j = j0 + tid;
    if (j < NQ) {
        float s = 0.0f;
        for (int m = 0; m < 101; ++m) s = fmaf(wsm_s[m], cs[tid + 100 - m], s);
        float fv = cs[tid + 50] - s;
        filt[j] = fv > 0.0f ? fv : 0.0f;
    }
    __syncthreads();

    // ---- last-arriving block runs comb+argmax (deterministic) ----
    __shared__ unsigned int lastflag;
    unsigned int* cnt = (unsigned int*)(spec + 8188);
    __threadfence();
    if (tid == 0) {
        unsigned int prev =
            __hip_atomic_fetch_add(cnt, 1u, __ATOMIC_ACQ_REL, __HIP_MEMORY_SCOPE_AGENT);
        lastflag = (prev == 32u) ? 1u : 0u;
    }
    __syncthreads();
    if (!lastflag) return;
    __threadfence();

    {
        __shared__ float fs[NQ];
        __shared__ float wd[84];
        __shared__ float sc[100];
        const int t = tid;
        for (int k = t; k < NQ; k += 256) fs[k] = filt[k];
        if (t < 84) wd[t] = wdet[t];
        __syncthreads();
        if (t < 100) {
            float s = 0.0f;
            for (int k = 0; k < 84; ++k) {
                int ix = t - 50 + 100 * k;
                if (ix >= 0) s = fmaf(wd[k], fs[ix], s);
            }
            sc[t] = s;
            out[1 + t] = s;
        }
        __syncthreads();
        if (t < 64) {    // wave argmax, first-max tie-break
            float v = (t < 100) ? sc[t] : -1e30f;
            int i = t;
            int t2 = t + 64;
            float v2 = (t2 < 100) ? sc[t2] : -1e30f;
            if (v2 > v) { v = v2; i = t2; }
#pragma unroll
            for (int off = 32; off; off >>= 1) {
                float ov = __shfl_xor(v, off, 64);
                int   oi = __shfl_xor(i, off, 64);
                if (ov > v || (ov == v && oi < i)) { v = ov; i = oi; }
            }
            if (t == 0) out[0] = (float)(i - 50);
        }
    }
}

extern "C" void kernel_launch(void* const* d_in, const int* in_sizes, int n_in,
                              void* d_out, int out_size, void* d_ws, size_t ws_size,
                              hipStream_t stream) {
    const float* audio = (const float*)d_in[0];
    const float* wsm   = (const float*)d_in[1];
    const float* wdet  = (const float*)d_in[2];
    float* out = (float*)d_out;
    float* ws  = (float*)d_ws;

    long cap = (long)(ws_size / sizeof(float) / NBINS) - 1;
    int P = (int)(cap < 4 ? 4 : (cap > 512 ? 512 : cap));
    P &= ~3;                               // multiple of 4 for the reduce
    float* spec    = ws;
    float* partial = ws + NBINS;           // P rows of 8192
    float* filt    = ws + 2 * NBINS;       // reuses partial rows (dead after reduce)

    // split mode: needs exactly-4-frames-per-block (P==512) and 2 spare rows
    // beyond partial for the 4 F tables (4 x 2048 cfloat = 64 KB).
    int doSplit = (P == 512 && cap >= (long)P + 3) ? 1 : 0;
    float* F = doSplit ? (ws + (size_t)(1 + P) * NBINS) : (float*)0;
    int fmax = doSplit ? 2048 : T_FRAMES;

    hipLaunchKernelGGL(fft_pow_kernel, dim3(P), dim3(512), 0, stream,
                       audio, partial, P, fmax, F);
    hipLaunchKernelGGL(reduce_kernel, dim3(64), dim3(128), 0, stream,
                       partial, spec, P, F);
    hipLaunchKernelGGL(cent_spline_comb_kernel, dim3(33), dim3(256), 0, stream,
                       spec, wsm, wdet, filt, out);
}

// Round 13
// 111.738 us; speedup vs baseline: 1.0183x; 1.0124x over previous
//
#include <hip/hip_runtime.h>
#include <math.h>

#define NBINS   8192
#define L_AUDIO 16777216
#define T_FRAMES 2049
#define NQ      8400
#define MUNK    8188

__device__ __forceinline__ int refl_idx(int m) {
    if (m < 0) m = -m;
    if (m >= L_AUDIO) m = 2 * L_AUDIO - 2 - m;
    return m;
}
__device__ __forceinline__ float2 cmul(float2 a, float2 b) {
    return make_float2(fmaf(a.x, b.x, -a.y * b.y), fmaf(a.x, b.y, a.y * b.x));
}
__device__ __forceinline__ float2 csq(float2 a) {
    return make_float2(fmaf(a.x, a.x, -a.y * a.y), 2.0f * a.x * a.y);
}
// Gentleman-Sande radix-4: w_r = W_L^{r*q0}; output r stays at q0 + r*L/4.
// With unit twiddles (q0=0), slot r holds bin-residue r (identity map).
__device__ __forceinline__ void r4(float2& x0, float2& x1, float2& x2, float2& x3,
                                   float2 w1, float2 w2, float2 w3) {
    float2 t0 = make_float2(x0.x + x2.x, x0.y + x2.y);
    float2 t1 = make_float2(x1.x + x3.x, x1.y + x3.y);
    float2 t2 = make_float2(x0.x - x2.x, x0.y - x2.y);
    float2 t3 = make_float2(x1.x - x3.x, x1.y - x3.y);
    float2 b1 = make_float2(t2.x + t3.y, t2.y - t3.x);   // t2 - i*t3
    float2 b3 = make_float2(t2.x - t3.y, t2.y + t3.x);   // t2 + i*t3
    x0 = make_float2(t0.x + t1.x, t0.y + t1.y);
    x1 = cmul(w1, b1);
    x2 = cmul(w2, make_float2(t0.x - t1.x, t0.y - t1.y));
    x3 = cmul(w3, b3);
}
// radix-8 on 8 elems at q0 + j*L/8; all twiddles derived from w = W_L^{q0}.
// Output slot j holds bin-residue rho(j) = (j&1)*4 + (j>>1)  [derived r8 map].
__device__ __forceinline__ void r8(float2 x[8], float2 w) {
    const float c = 0.70710678118654752f;
    float2 w2 = csq(w), w3 = cmul(w, w2), w4 = csq(w2);
    r4(x[0], x[2], x[4], x[6], w, w2, w3);
    float2 wE   = make_float2(c * (w.x + w.y),  c * (w.y - w.x));     // w*e^{-i pi/4}
    float2 w2E2 = make_float2(w2.y, -w2.x);                           // w2*(-i)
    float2 w3E3 = make_float2(c * (w3.y - w3.x), -c * (w3.x + w3.y)); // w3*e^{-i3pi/4}
    r4(x[1], x[3], x[5], x[7], wE, w2E2, w3E3);
#pragma unroll
    for (int r = 0; r < 4; ++r) {
        float2 a = x[2 * r], b = x[2 * r + 1];
        x[2 * r]     = make_float2(a.x + b.x, a.y + b.y);
        float2 d     = make_float2(a.x - b.x, a.y - b.y);
        x[2 * r + 1] = cmul(w4, d);
    }
}
// inverse of rho: slot index holding residue r in an r8 output group
__device__ __forceinline__ int jof(int r) {
    return ((r >> 1) & 1) * 4 + (r & 1) * 2 + (r >> 2);
}
// position of logical bin m in the 2048-pt [8,8,8,4] GS chain output
// (final radix-4 has unit twiddles -> identity slot map for the top digit)
__device__ __forceinline__ int posOf2048(int m) {
    return 256 * jof(m & 7) + 32 * jof((m >> 3) & 7)
         + 4 * jof((m >> 6) & 7) + (m >> 9);
}

// ---------------- Kernel A: 512 threads, in-place 8192-pt complex FFT as
// 3x radix-8 + fused (radix-8 x2 + radix-2 in regs); window+pack fused into
// pass 1. Body = round-10 (best-measured family, 111.8-112.1us). Split mode
// (fmax==2048): every block does exactly 4 frames; frame 2048 via blocks
// 4..7 as 4 decimated 2048-pt FFTs, combined in the reduce. Round-13:
// setprio reverted (r12: null/slightly negative — no role-split for the
// scheduler to arbitrate between identical free-running blocks). Falsified
// levers (sessions 1-12): convoy-breaking, stagger, frame reassignment,
// tail work/placement, register-untangle, setprio. fft is latency-bound at
// its LDS-forced occupancy (2 blocks/CU) and register wall (~116/128). ---
__global__ __launch_bounds__(512, 2) void fft_pow_kernel(
        const float* __restrict__ audio, float* __restrict__ partial, int P,
        int fmax, float* __restrict__ Fout) {
    __shared__ float2 buf[8718];   // phi(p) = p + (p>>4) + (p>>9), max 8717
    const int t = threadIdx.x;

    if (blockIdx.x == 0 && t == 0) {   // counter lives at spec[8188]
        unsigned int* cz = (unsigned int*)(partial - 4);
        cz[0] = 0u;
    }

    const int phit  = t + (t >> 4);                         // phi(t), t < 512
    const int q2    = t & 127;
    const int base2 = 1090 * (t >> 7) + q2 + (q2 >> 4);     // pass2 base
    const int base3 = 136 * (t >> 4) + ((t >> 4) >> 2) + (t & 15);
    const int base4 = 17 * t + (t >> 5);
    const int tp    = (512 - t) & 511;
    const int PBt = (t & 3) * 2048 + ((t >> 2) & 1) * 1024 + ((t >> 3) & 3) * 256
                  + ((t >> 5) & 1) * 128 + ((t >> 6) & 3) * 32 + ((t >> 8) & 1) * 16;
    const int PBp = (tp & 3) * 2048 + ((tp >> 2) & 1) * 1024 + ((tp >> 3) & 3) * 256
                  + ((tp >> 5) & 1) * 128 + ((tp >> 6) & 3) * 32 + ((tp >> 8) & 1) * 16;
    const int ubA = PBt + (PBt >> 4) + (PBt >> 9);
    const int ubB = PBp + (PBp >> 4) + (PBp >> 9);

    const float2 ONE = make_float2(1.0f, 0.0f);
    const float2 K8  = make_float2(0.92387953251128674f, -0.38268343236508977f); // e^{-i pi/8}
    const float2 KD  = make_float2(0.99999992646574f, -0.00038349518757f);       // e^{-i pi/8192}
    float2 wU  = make_float2(cospif((float)t * (1.0f / 8192.0f)),
                             -sinpif((float)t * (1.0f / 8192.0f)));  // W_16384^t
    float2 w1  = csq(wU);                                            // W_8192^t
    float2 wodd = cmul(w1, KD);                                      // e^{-i pi(2t+1)/8192}
    float2 w2t = make_float2(cospif((float)q2 * (1.0f / 512.0f)),
                             -sinpif((float)q2 * (1.0f / 512.0f)));  // W_1024^(t&127)
    float2 w3t = make_float2(cospif((float)(t & 15) * (1.0f / 64.0f)),
                             -sinpif((float)(t & 15) * (1.0f / 64.0f))); // W_128^(t&15)
    const float K16c[16] = {1.0f, 0.98078528040323044f, 0.92387953251128674f,
        0.83146961230254524f, 0.70710678118654752f, 0.55557023301960222f,
        0.38268343236508977f, 0.19509032201612825f, 0.0f, -0.19509032201612825f,
        -0.38268343236508977f, -0.55557023301960222f, -0.70710678118654752f,
        -0.83146961230254524f, -0.92387953251128674f, -0.98078528040323044f};
    const float K16s[16] = {0.0f, -0.19509032201612825f, -0.38268343236508977f,
        -0.55557023301960222f, -0.70710678118654752f, -0.83146961230254524f,
        -0.92387953251128674f, -0.98078528040323044f, -1.0f, -0.98078528040323044f,
        -0.92387953251128674f, -0.83146961230254524f, -0.70710678118654752f,
        -0.55557023301960222f, -0.38268343236508977f, -0.19509032201612825f};
    // window rotation: cos/sin(pi u/8), u in [0,16)
    const float W16C[16] = {1.0f, 0.92387953251128674f, 0.70710678118654752f,
        0.38268343236508977f, 0.0f, -0.38268343236508977f, -0.70710678118654752f,
        -0.92387953251128674f, -1.0f, -0.92387953251128674f, -0.70710678118654752f,
        -0.38268343236508977f, 0.0f, 0.38268343236508977f, 0.70710678118654752f,
        0.92387953251128674f};
    const float W16S[16] = {0.0f, 0.38268343236508977f, 0.70710678118654752f,
        0.92387953251128674f, 1.0f, 0.92387953251128674f, 0.70710678118654752f,
        0.38268343236508977f, 0.0f, -0.38268343236508977f, -0.70710678118654752f,
        -0.92387953251128674f, -1.0f, -0.92387953251128674f, -0.70710678118654752f,
        -0.38268343236508977f};

    float acc[16];
#pragma unroll
    for (int u = 0; u < 16; ++u) acc[u] = 0.0f;

    for (int f = blockIdx.x; f < fmax; f += P) {
        __syncthreads();   // previous frame's untangle reads vs pass-1 writes
        // ---- pass 1 (fused window+pack): L=8192, q0 = t + 512g ----
        const bool interior = (f != 0) && (f != T_FRAMES - 1);
        const float2* au2 = (const float2*)audio + 4096 * (f - 1);
        const int baseS = f * 8192 - 8192;
#pragma unroll 1
        for (int g = 0; g < 2; ++g) {
            float2 x[8];
            if (interior) {
#pragma unroll
                for (int j = 0; j < 8; ++j) {
                    int idx = t + 512 * g + 1024 * j;
                    float2 p = au2[idx];
                    const int uix = g + 2 * j;
                    float c0 = 0.5f - 0.5f * (w1.x * W16C[uix] + w1.y * W16S[uix]);
                    float c1 = 0.5f - 0.5f * (wodd.x * W16C[uix] + wodd.y * W16S[uix]);
                    x[j] = make_float2(p.x * c0, p.y * c1);
                }
            } else {
#pragma unroll
                for (int j = 0; j < 8; ++j) {
                    int idx = t + 512 * g + 1024 * j;
                    float a0 = audio[refl_idx(baseS + 2 * idx)];
                    float a1 = audio[refl_idx(baseS + 2 * idx + 1)];
                    const int uix = g + 2 * j;
                    float c0 = 0.5f - 0.5f * (w1.x * W16C[uix] + w1.y * W16S[uix]);
                    float c1 = 0.5f - 0.5f * (wodd.x * W16C[uix] + wodd.y * W16S[uix]);
                    x[j] = make_float2(a0 * c0, a1 * c1);
                }
            }
            float2 w = g ? cmul(w1, K8) : w1;
            r8(x, w);
#pragma unroll
            for (int j = 0; j < 8; ++j) buf[phit + 545 * g + 1090 * j] = x[j];
        }
        __syncthreads();
        // pass 2: L=1024, B = (t>>7)+4g, q0 = t&127, stride 128
#pragma unroll 1
        for (int g = 0; g < 2; ++g) {
            float2 x[8];
            const int bs = base2 + 4360 * g;
#pragma unroll
            for (int j = 0; j < 8; ++j) x[j] = buf[bs + 136 * j + (j >> 2)];
            r8(x, w2t);
#pragma unroll
            for (int j = 0; j < 8; ++j) buf[bs + 136 * j + (j >> 2)] = x[j];
        }
        __syncthreads();
        // pass 3: L=128, B = (t>>4)+32g, q0 = t&15, stride 16
#pragma unroll 1
        for (int g = 0; g < 2; ++g) {
            float2 x[8];
            const int bs = base3 + 4360 * g;
#pragma unroll
            for (int j = 0; j < 8; ++j) x[j] = buf[bs + 17 * j];
            r8(x, w3t);
#pragma unroll
            for (int j = 0; j < 8; ++j) buf[bs + 17 * j] = x[j];
        }
        __syncthreads();
        // pass 4+5 fused: thread t owns logical [16t,16t+16); radix-8 on both
        // parity groups in registers; radix-2 pairs are (a[j], x[j]).
        {
            float2 a[8], x[8];
#pragma unroll
            for (int j = 0; j < 8; ++j) a[j] = buf[base4 + 2 * j];
            r8(a, ONE);
#pragma unroll
            for (int j = 0; j < 8; ++j) x[j] = buf[base4 + 1 + 2 * j];
            r8(x, K8);
#pragma unroll
            for (int j = 0; j < 8; ++j) {
                buf[base4 + 2 * j]     = make_float2(a[j].x + x[j].x, a[j].y + x[j].y);
                buf[base4 + 2 * j + 1] = make_float2(a[j].x - x[j].x, a[j].y - x[j].y);
            }
        }
        __syncthreads();
        // untangle real FFT at digit-reversed positions, power, log
#pragma unroll
        for (int u = 0; u < 16; ++u) {
            const int off = (u & 3) * 4 + ((u >> 2) & 1) * 2 + (u >> 3);
            int u2 = t ? (15 - u) : ((16 - u) & 15);
            int off2 = (u2 & 3) * 4 + ((u2 >> 2) & 1) * 2 + (u2 >> 3);
            float2 A = buf[ubA + off];
            float2 B = buf[ubB + off2];
            float Xer = 0.5f * (A.x + B.x);
            float Xei = 0.5f * (A.y - B.y);
            float Xor = 0.5f * (A.y + B.y);
            float Xoi = -0.5f * (A.x - B.x);
            float2 w = cmul(wU, make_float2(K16c[u], K16s[u]));  // W_16384^{t+512u}
            float Xr = Xer + Xor * w.x - Xoi * w.y;
            float Xi = Xei + Xor * w.y + Xoi * w.x;
            float pw = Xr * Xr + Xi * Xi;
            acc[u] += __logf(fmaf(100.0f, pw, 1.0f));
        }
    }
#pragma unroll
    for (int u = 0; u < 16; ++u)
        partial[(size_t)blockIdx.x * NBINS + t + 512 * u] = acc[u];

    // ---- split mode: blocks 4..7 compute frame 2048's residue-class FFTs --
    // Block 4+r computes F_r = FFT_2048(z[4n+r]) via GS [8,8,8,4];
    // 256 threads x 8 elems; LDS map phi2(p) = p + (p>>4).
    if (Fout != (float*)0 && blockIdx.x >= 4 && blockIdx.x < 8) {
        const int r = blockIdx.x - 4;
        __syncthreads();                 // main loop's untangle reads done
        const int baseS = 2048 * 8192 - 8192;
        const int phit2 = t + (t >> 4);
        // wr = e^{-i pi(8t+2r)/8192}; hann via W16 tables at uix = 2j;
        // odd sample via wro = wr*KD.
        float2 wr = make_float2(cospif((float)(8 * t + 2 * r) * (1.0f / 8192.0f)),
                                -sinpif((float)(8 * t + 2 * r) * (1.0f / 8192.0f)));
        float2 wro = cmul(wr, KD);
        if (t < 256) {   // pass 1: L=2048, elems n = t + 256j, w = W_2048^t
            float2 x[8];
#pragma unroll
            for (int j = 0; j < 8; ++j) {
                int e0 = baseS + 8 * t + 2 * r + 2048 * j;   // audio idx of 2s
                float a0 = audio[refl_idx(e0)];
                float a1 = audio[refl_idx(e0 + 1)];
                float c0 = 0.5f - 0.5f * (wr.x * W16C[2 * j] + wr.y * W16S[2 * j]);
                float c1 = 0.5f - 0.5f * (wro.x * W16C[2 * j] + wro.y * W16S[2 * j]);
                x[j] = make_float2(a0 * c0, a1 * c1);
            }
            float2 w = make_float2(cospif((float)t * (1.0f / 1024.0f)),
                                   -sinpif((float)t * (1.0f / 1024.0f)));
            r8(x, w);
#pragma unroll
            for (int j = 0; j < 8; ++j) buf[phit2 + 272 * j] = x[j];
        }
        __syncthreads();
        if (t < 256) {   // pass 2: L=256, B = t>>5, q = t&31
            const int q = t & 31;
            const int bs = 272 * (t >> 5) + q + (q >> 4);
            float2 x[8];
#pragma unroll
            for (int j = 0; j < 8; ++j) x[j] = buf[bs + 34 * j];
            float2 w = make_float2(cospif((float)q * (1.0f / 128.0f)),
                                   -sinpif((float)q * (1.0f / 128.0f)));
            r8(x, w);
#pragma unroll
            for (int j = 0; j < 8; ++j) buf[bs + 34 * j] = x[j];
        }
        __syncthreads();
        if (t < 256) {   // pass 3: L=32, B = t>>2, q = t&3
            const int q = t & 3;
            const int bs = 34 * (t >> 2) + q;
            float2 x[8];
#pragma unroll
            for (int j = 0; j < 8; ++j) x[j] = buf[bs + 4 * j + (j >> 2)];
            float2 w = make_float2(cospif((float)q * (1.0f / 16.0f)),
                                   -sinpif((float)q * (1.0f / 16.0f)));
            r8(x, w);
#pragma unroll
            for (int j = 0; j < 8; ++j) buf[bs + 4 * j + (j >> 2)] = x[j];
        }
        __syncthreads();
        if (t < 256) {   // pass 4: radix-4 on contiguous groups 2t, 2t+1
#pragma unroll
            for (int gg = 0; gg < 2; ++gg) {
                int g = 2 * t + gg;
                int bs = 4 * g + (g >> 2);
                float2 x0 = buf[bs], x1 = buf[bs + 1];
                float2 x2 = buf[bs + 2], x3 = buf[bs + 3];
                r4(x0, x1, x2, x3, ONE, ONE, ONE);
                buf[bs] = x0; buf[bs + 1] = x1; buf[bs + 2] = x2; buf[bs + 3] = x3;
            }
        }
        __syncthreads();
        if (t < 256) {   // store F_r[p] = buf[phi2(p)], p = t + 256j
            float2* fo = (float2*)Fout + r * 2048;
#pragma unroll
            for (int j = 0; j < 8; ++j) fo[t + 256 * j] = buf[phit2 + 272 * j];
        }
    }
}

// ---------------- Kernel B: parallel deterministic reduce -------------------
// float4 loads, order bit-identical to the verified scalar kernel. In split
// mode (F != 0), adds frame 2048's log-power per bin: X[k] = 4-term Horner
// over F_r[k mod 2048] with w = W_8192^k, then the standard rfft untangle +
// power + log (added LAST -> deterministic).
__global__ __launch_bounds__(128) void reduce_kernel(
        const float* __restrict__ partial, float* __restrict__ spec, int P,
        const float* __restrict__ F) {
    __shared__ float4 s[4][33];
    const int bin0 = blockIdx.x * 128;
    const int co = threadIdx.x & 31;
    const int g  = threadIdx.x >> 5;       // 0..3
    const int rows = P >> 2;               // P/4
    const int RS = NBINS / 4;              // float4 row stride
    const float4* base = (const float4*)(partial + (size_t)g * rows * NBINS + bin0) + co;
    float4 a0 = make_float4(0.f, 0.f, 0.f, 0.f);
    float4 a1 = make_float4(0.f, 0.f, 0.f, 0.f);
    int r = 0;
    for (; r + 16 <= rows; r += 16) {
        float4 l[16];
#pragma unroll
        for (int q = 0; q < 16; ++q) l[q] = base[(size_t)(r + q) * RS];
#pragma unroll
        for (int q = 0; q < 16; q += 2) {
            a0.x += l[q].x; a0.y += l[q].y; a0.z += l[q].z; a0.w += l[q].w;
            a1.x += l[q+1].x; a1.y += l[q+1].y; a1.z += l[q+1].z; a1.w += l[q+1].w;
        }
    }
    for (; r + 2 <= rows; r += 2) {
        float4 l0 = base[(size_t)r * RS];
        float4 l1 = base[(size_t)(r + 1) * RS];
        a0.x += l0.x; a0.y += l0.y; a0.z += l0.z; a0.w += l0.w;
        a1.x += l1.x; a1.y += l1.y; a1.z += l1.z; a1.w += l1.w;
    }
    for (; r < rows; ++r) {
        float4 l0 = base[(size_t)r * RS];
        a0.x += l0.x; a0.y += l0.y; a0.z += l0.z; a0.w += l0.w;
    }
    s[g][co] = make_float4(a0.x + a1.x, a0.y + a1.y, a0.z + a1.z, a0.w + a1.w);
    __syncthreads();
    if (threadIdx.x < 32) {
        float4 s0 = s[0][threadIdx.x], s1 = s[1][threadIdx.x];
        float4 s2 = s[2][threadIdx.x], s3 = s[3][threadIdx.x];
        float4 v = make_float4((s0.x + s1.x) + (s2.x + s3.x),
                               (s0.y + s1.y) + (s2.y + s3.y),
                               (s0.z + s1.z) + (s2.z + s3.z),
                               (s0.w + s1.w) + (s2.w + s3.w));
        if (F != (const float*)0) {
            const float2* Fb = (const float2*)F;   // 4 tables of 2048
            float* vv = &v.x;
#pragma unroll
            for (int c = 0; c < 4; ++c) {
                int b = bin0 + 4 * threadIdx.x + c;
                // X(b) via 4-term Horner
                int kh = posOf2048(b & 2047);
                float2 wk = make_float2(cospif((float)b * (1.0f / 4096.0f)),
                                        -sinpif((float)b * (1.0f / 4096.0f)));
                float2 Xk = Fb[6144 + kh];
                Xk = cmul(wk, Xk);
                Xk.x += Fb[4096 + kh].x; Xk.y += Fb[4096 + kh].y;
                Xk = cmul(wk, Xk);
                Xk.x += Fb[2048 + kh].x; Xk.y += Fb[2048 + kh].y;
                Xk = cmul(wk, Xk);
                Xk.x += Fb[kh].x; Xk.y += Fb[kh].y;
                // X(pb), pb = (8192-b) mod 8192
                int pb = (8192 - b) & 8191;
                int ph = posOf2048(pb & 2047);
                float2 wp = make_float2(cospif((float)pb * (1.0f / 4096.0f)),
                                        -sinpif((float)pb * (1.0f / 4096.0f)));
                float2 Xp = Fb[6144 + ph];
                Xp = cmul(wp, Xp);
                Xp.x += Fb[4096 + ph].x; Xp.y += Fb[4096 + ph].y;
                Xp = cmul(wp, Xp);
                Xp.x += Fb[2048 + ph].x; Xp.y += Fb[2048 + ph].y;
                Xp = cmul(wp, Xp);
                Xp.x += Fb[ph].x; Xp.y += Fb[ph].y;
                // rfft untangle + power + log
                float Xer = 0.5f * (Xk.x + Xp.x);
                float Xei = 0.5f * (Xk.y - Xp.y);
                float Xor = 0.5f * (Xk.y + Xp.y);
                float Xoi = -0.5f * (Xk.x - Xp.x);
                float2 wu = make_float2(cospif((float)b * (1.0f / 8192.0f)),
                                        -sinpif((float)b * (1.0f / 8192.0f)));
                float Xr = Xer + Xor * wu.x - Xoi * wu.y;
                float Xi = Xei + Xor * wu.y + Xoi * wu.x;
                float pw = Xr * Xr + Xi * Xi;
                vv[c] += __logf(fmaf(100.0f, pw, 1.0f));
            }
        }
        if (!(blockIdx.x == 63 && threadIdx.x == 31))   // keep counter cell
            ((float4*)(spec + bin0))[threadIdx.x] = v;
    }
}

// ---------------- Kernel C: spline + smooth + relu, then the LAST-arriving
// block runs the comb+argmax inline (no-spin last-block pattern). 33 blocks.
__global__ __launch_bounds__(256) void cent_spline_comb_kernel(
        const float* __restrict__ spec, const float* __restrict__ wsm,
        const float* __restrict__ wdet, float* __restrict__ filt,
        float* __restrict__ out) {
    __shared__ float ys[768];
    __shared__ float dps[704];
    __shared__ float Ms[640];
    __shared__ float cs[356];
    __shared__ float wsm_s[101];
    __shared__ float invden_s[64];
    const int tid = threadIdx.x;
    const int j0 = blockIdx.x * 256;
    const float h = 22050.0f / 16384.0f;
    const float hh = h * h;

    if (tid == 0) {
        double v = 0.25;
        invden_s[0] = 0.25f;
        for (int i = 1; i < 64; ++i) { v = 1.0 / (4.0 - v); invden_s[i] = (float)v; }
    }
    for (int r = tid; r < 101; r += 256) wsm_s[r] = wsm[r];

    const int jLo = max(j0 - 50, 0);
    const int jHi = min(j0 + 305, NQ - 1);
    const float xqLo = (float)(440.0 * exp2(((double)jLo * 0.01 - 45.0) * (1.0 / 12.0)));
    const float xqHi = (float)(440.0 * exp2(((double)jHi * 0.01 - 45.0) * (1.0 / 12.0)));
    const int iLo = min(max((int)floorf(xqLo / h), 0), 8190);
    const int iHi = min(max((int)floorf(xqHi / h), 0), 8190);
    const int pLo = max(iLo - 2, 0);
    const int pHi = min(iHi - 1, MUNK - 1);
    const int bHi = min(pHi + 64, MUNK - 1);
    const int yLo = max(pLo - 64, 0);
    const int yHi = bHi + 3;
    const int ny  = yHi - yLo + 1;

    for (int k = tid; k < ny; k += 256) ys[k] = spec[yLo + k];
    __syncthreads();
    const float cst = invden_s[63];   // 2 - sqrt(3)

    {
        const int nch = (bHi - pLo + 32) >> 5;
        if (tid < nch) {
            const int s = pLo + (tid << 5);
            const int e = min(s + 31, bHi);
            const int ws = max(s - 64, 0);
            float dprev = 0.0f;
            for (int i = ws; i <= e; ++i) {
                float d1 = (ys[i + 1 - yLo] - 2.0f * ys[i + 2 - yLo]
                            + ys[i + 3 - yLo]) / hh;
                float r = 6.0f * d1;
                if (i == 0) r -= (ys[0] - 2.0f * ys[1] + ys[2]) / hh;
                float val = (i == 0) ? r : (r - dprev);
                float dpv = val * ((i < 64) ? invden_s[i] : cst);
                if (i >= s) dps[i - pLo] = dpv;
                dprev = dpv;
            }
        }
    }
    __syncthreads();
    {
        const int nch = (pHi - pLo + 32) >> 5;
        if (tid < nch) {
            const int s = pLo + (tid << 5);
            const int e = min(s + 31, pHi);
            const int ws2 = min(e + 64, bHi);
            float xnext = 0.0f;
            for (int i = ws2; i >= s; --i) {
                float cp = (i == MUNK - 1) ? 0.0f : ((i < 64) ? invden_s[i] : cst);
                float xv = dps[i - pLo] - cp * xnext;
                if (i <= e) Ms[2 + i - iLo] = xv;
                xnext = xv;
            }
        }
    }
    __syncthreads();
    for (int r = tid; r < 356; r += 256) {
        int j = j0 - 50 + r;
        float v = 0.0f;
        if (j >= 0 && j < NQ) {
            double e = ((double)j * 0.01 - 45.0) * (1.0 / 12.0);
            float xq = (float)(440.0 * exp2(e));
            int i = min(max((int)floorf(xq / h), 0), 8190);
            float tt = xq - (float)i * h;
            float uu = h - tt;
            float Mi = Ms[i - iLo], Mi1 = Ms[i + 1 - iLo];
            float yi = ys[i - yLo], yi1 = ys[i + 1 - yLo];
            v = (Mi * uu * uu * uu + Mi1 * tt * tt * tt) / (6.0f * h)
              + (yi - Mi * hh / 6.0f) * uu / h
              + (yi1 - Mi1 * hh / 6.0f) * tt / h;
        }
        cs[r] = v;
    }
    __syncthreads();
    int j = j0 + tid;
    if (j < NQ) {
        float s = 0.0f;
        for (int m = 0; m < 101; ++m) s = fmaf(wsm_s[m], cs[tid + 100 - m], s);
        float fv = cs[tid + 50] - s;
        filt[j] = fv > 0.0f ? fv : 0.0f;
    }
    __syncthreads();

    // ---- last-arriving block runs comb+argmax (deterministic) ----
    __shared__ unsigned int lastflag;
    unsigned int* cnt = (unsigned int*)(spec + 8188);
    __threadfence();
    if (tid == 0) {
        unsigned int prev =
            __hip_atomic_fetch_add(cnt, 1u, __ATOMIC_ACQ_REL, __HIP_MEMORY_SCOPE_AGENT);
        lastflag = (prev == 32u) ? 1u : 0u;
    }
    __syncthreads();
    if (!lastflag) return;
    __threadfence();

    {
        __shared__ float fs[NQ];
        __shared__ float wd[84];
        __shared__ float sc[100];
        const int t = tid;
        for (int k = t; k < NQ; k += 256) fs[k] = filt[k];
        if (t < 84) wd[t] = wdet[t];
        __syncthreads();
        if (t < 100) {
            float s = 0.0f;
            for (int k = 0; k < 84; ++k) {
                int ix = t - 50 + 100 * k;
                if (ix >= 0) s = fmaf(wd[k], fs[ix], s);
            }
            sc[t] = s;
            out[1 + t] = s;
        }
        __syncthreads();
        if (t < 64) {    // wave argmax, first-max tie-break
            float v = (t < 100) ? sc[t] : -1e30f;
            int i = t;
            int t2 = t + 64;
            float v2 = (t2 < 100) ? sc[t2] : -1e30f;
            if (v2 > v) { v = v2; i = t2; }
#pragma unroll
            for (int off = 32; off; off >>= 1) {
                float ov = __shfl_xor(v, off, 64);
                int   oi = __shfl_xor(i, off, 64);
                if (ov > v || (ov == v && oi < i)) { v = ov; i = oi; }
            }
            if (t == 0) out[0] = (float)(i - 50);
        }
    }
}

extern "C" void kernel_launch(void* const* d_in, const int* in_sizes, int n_in,
                              void* d_out, int out_size, void* d_ws, size_t ws_size,
                              hipStream_t stream) {
    const float* audio = (const float*)d_in[0];
    const float* wsm   = (const float*)d_in[1];
    const float* wdet  = (const float*)d_in[2];
    float* out = (float*)d_out;
    float* ws  = (float*)d_ws;

    long cap = (long)(ws_size / sizeof(float) / NBINS) - 1;
    int P = (int)(cap < 4 ? 4 : (cap > 512 ? 512 : cap));
    P &= ~3;                               // multiple of 4 for the reduce
    float* spec    = ws;
    float* partial = ws + NBINS;           // P rows of 8192
    float* filt    = ws + 2 * NBINS;       // reuses partial rows (dead after reduce)

    // split mode: needs exactly-4-frames-per-block (P==512) and 2 spare rows
    // beyond partial for the 4 F tables (4 x 2048 cfloat = 64 KB).
    int doSplit = (P == 512 && cap >= (long)P + 3) ? 1 : 0;
    float* F = doSplit ? (ws + (size_t)(1 + P) * NBINS) : (float*)0;
    int fmax = doSplit ? 2048 : T_FRAMES;

    hipLaunchKernelGGL(fft_pow_kernel, dim3(P), dim3(512), 0, stream,
                       audio, partial, P, fmax, F);
    hipLaunchKernelGGL(reduce_kernel, dim3(64), dim3(128), 0, stream,
                       partial, spec, P, F);
    hipLaunchKernelGGL(cent_spline_comb_kernel, dim3(33), dim3(256), 0, stream,
                       spec, wsm, wdet, filt, out);
}